// Round 1
// baseline (250.846 us; speedup 1.0000x reference)
//
#include <hip/hip_runtime.h>
#include <hip/hip_bf16.h>

// GridPooling: occupancy -> attention-pool -> GEMM -> batch-norm(axis0) -> relu
// Round 0: correctness-first fp32 pipeline with dtype sniffing (bf16 vs f32
// inputs). ws layout (floats):
//   [0 .. 1594368)        converted f32 inputs (concatenated, b_full skipped)
//   [1594368 .. 1725440)  occ  (2048 x 64)
//   [1725440 .. 3822592)  pool (2048 x 1024)
//   [3822592 .. 5919744)  y    (2048 x 1024)
//   [5919744 .. 5921792)  stats (colsum[1024], colsumsq[1024])
//   [5921792]             flag (int: 1 = inputs are bf16)
// Total ~23.7 MB.

#define NPED 2048
#define NA   1024
#define NH   64
#define NG2  64
#define NPTS 4096

struct InPtrs { const void* p[15]; };

// ---------------------------------------------------------------- detect dtype
__global__ void k_detect(const unsigned short* __restrict__ h, int* __restrict__ flag) {
  __shared__ int bad_sh;
  if (threadIdx.x == 0) bad_sh = 0;
  __syncthreads();
  int bad = 0;
  for (int i = threadIdx.x; i < 4096; i += 256) {
    float v = __uint_as_float(((unsigned int)h[i]) << 16);
    if (!(fabsf(v) <= 1e4f)) bad = 1;   // catches inf/nan too
  }
  if (bad) atomicOr(&bad_sh, 1);
  __syncthreads();
  if (threadIdx.x == 0) flag[0] = (bad_sh == 0) ? 1 : 0;
}

// ---------------------------------------------------------------- convert all inputs -> f32
// segment order: h, end_pos, rel_pos, scene, W_enc, b_enc, W_dec, b_dec,
//                w_full, W_out, b_out, W_mlp, b_mlp, gamma, beta
__global__ void k_convert(InPtrs ptrs, const int* __restrict__ flag, float* __restrict__ dst) {
  const int ends[15] = {131072,135168,139264,401408,402432,403456,468992,470016,
                        471040,541696,542720,1591296,1592320,1593344,1594368};
  int idx = (blockIdx.x * 256 + threadIdx.x) * 4;   // all segment sizes are mult of 4
  int seg = 0, base = 0;
#pragma unroll
  for (int s = 0; s < 14; s++) {
    if (idx >= ends[s]) { seg = s + 1; base = ends[s]; }
  }
  int off = idx - base;
  float4 o;
  if (flag[0]) {
    const unsigned int* src = (const unsigned int*)ptrs.p[seg];
    uint2 u = *(const uint2*)(src + (off >> 1));
    o.x = __uint_as_float((u.x & 0xFFFFu) << 16);
    o.y = __uint_as_float(u.x & 0xFFFF0000u);
    o.z = __uint_as_float((u.y & 0xFFFFu) << 16);
    o.w = __uint_as_float(u.y & 0xFFFF0000u);
  } else {
    o = *(const float4*)((const float*)ptrs.p[seg] + off);
  }
  *(float4*)(dst + idx) = o;
}

// ---------------------------------------------------------------- occupancy histogram
__global__ __launch_bounds__(256) void k_occupancy(const float* __restrict__ end_pos,
                                                   const float* __restrict__ scene,
                                                   float* __restrict__ occ) {
  int i = blockIdx.x;            // ped
  int s = i >> 6;                // sequence (64 peds/seq)
  __shared__ float cnt[NG2];
  if (threadIdx.x < NG2) cnt[threadIdx.x] = 0.0f;
  __syncthreads();
  float ex = end_pos[2 * i], ey = end_pos[2 * i + 1];
  float tlx = ex - 1.0f, tly = ey + 1.0f, brx = ex + 1.0f, bry = ey - 1.0f;
  const float2* sp = (const float2*)(scene + (size_t)s * NPTS * 2);
  for (int p = threadIdx.x; p < NPTS; p += 256) {
    float2 pt = sp[p];
    float sx = pt.x, sy = pt.y;
    bool oob = (sx >= brx) || (sx <= tlx) || (sy >= tly) || (sy <= bry);
    if (!oob) {
      // exact same fp ops as reference: (d / 2) * 8 == d * 0.5 * 8 (pow2 exact)
      int cx = (int)floorf((sx - tlx) * 0.5f * 8.0f);
      int cy = (int)floorf((tly - sy) * 0.5f * 8.0f);
      int cell = cx + cy * 8;
      if (cell >= 0 && cell < NG2) atomicAdd(&cnt[cell], 1.0f);
    }
  }
  __syncthreads();
  if (threadIdx.x < NG2) occ[i * NG2 + threadIdx.x] = cnt[threadIdx.x];
}

// ---------------------------------------------------------------- fused attention + pool
__global__ __launch_bounds__(256) void k_attn_pool(
    const float* __restrict__ h_states, const float* __restrict__ end_pos,
    const float* __restrict__ rel_pos, const float* __restrict__ occ,
    const float* __restrict__ W_enc, const float* __restrict__ b_enc,
    const float* __restrict__ W_dec, const float* __restrict__ b_dec,
    const float* __restrict__ w_full,
    const float* __restrict__ W_out, const float* __restrict__ b_out,
    float* __restrict__ pool) {
  int i = blockIdx.x;
  int tid = threadIdx.x;
  int wave = tid >> 6, lane = tid & 63;
  int a = wave * 256 + lane * 4;          // 4 consecutive feature cols

  __shared__ float h_sh[NH];
  __shared__ float occ_sh[NG2];
  __shared__ float ew[4][NG2];
  __shared__ float ctx_sh;

  if (tid < NH) h_sh[tid] = h_states[i * NH + tid];
  else if (tid < NH + NG2) occ_sh[tid - NH] = occ[i * NG2 + (tid - NH)];
  __syncthreads();

  // hd = b_enc + b_dec + h . W_dec   (per thread: 4 cols)
  float4 hd = *(const float4*)(b_enc + a);
  {
    float4 bd = *(const float4*)(b_dec + a);
    hd.x += bd.x; hd.y += bd.y; hd.z += bd.z; hd.w += bd.w;
  }
#pragma unroll 8
  for (int k = 0; k < NH; k++) {
    float hk = h_sh[k];
    float4 w = *(const float4*)(W_dec + k * NA + a);
    hd.x = fmaf(hk, w.x, hd.x); hd.y = fmaf(hk, w.y, hd.y);
    hd.z = fmaf(hk, w.z, hd.z); hd.w = fmaf(hk, w.w, hd.w);
  }
  float4 we = *(const float4*)(W_enc + a);
  float4 wf = *(const float4*)(w_full + a);

  // e[g] = sum_a relu(occ[g]*W_enc[a] + hd[a]) * w_full[a]
  for (int g = 0; g < NG2; g++) {
    float c = occ_sh[g];
    float p = fmaxf(fmaf(c, we.x, hd.x), 0.0f) * wf.x
            + fmaxf(fmaf(c, we.y, hd.y), 0.0f) * wf.y
            + fmaxf(fmaf(c, we.z, hd.z), 0.0f) * wf.z
            + fmaxf(fmaf(c, we.w, hd.w), 0.0f) * wf.w;
#pragma unroll
    for (int off = 32; off > 0; off >>= 1) p += __shfl_down(p, off);
    if (lane == 0) ew[wave][g] = p;
  }
  __syncthreads();

  // softmax over 64 cells + ctx = sum alpha*occ   (wave 0, lane == g)
  if (tid < NG2) {
    int g = tid;
    float e = ew[0][g] + ew[1][g] + ew[2][g] + ew[3][g];
    float m = e;
#pragma unroll
    for (int off = 32; off > 0; off >>= 1) m = fmaxf(m, __shfl_xor(m, off));
    float xe = __expf(e - m);
    float den = xe;
#pragma unroll
    for (int off = 32; off > 0; off >>= 1) den += __shfl_xor(den, off);
    float cp = xe * occ_sh[g];
#pragma unroll
    for (int off = 32; off > 0; off >>= 1) cp += __shfl_xor(cp, off);
    if (g == 0) ctx_sh = cp / den;
  }
  __syncthreads();

  // pool = [ctx, h, ep, rel] . W_out + b_out
  float ctx = ctx_sh;
  float epx = end_pos[2 * i], epy = end_pos[2 * i + 1];
  float rlx = rel_pos[2 * i], rly = rel_pos[2 * i + 1];
  float4 acc = *(const float4*)(b_out + a);
  {
    float4 w = *(const float4*)(W_out + a);   // row 0: ctx
    acc.x = fmaf(ctx, w.x, acc.x); acc.y = fmaf(ctx, w.y, acc.y);
    acc.z = fmaf(ctx, w.z, acc.z); acc.w = fmaf(ctx, w.w, acc.w);
  }
#pragma unroll 8
  for (int k = 0; k < NH; k++) {
    float hk = h_sh[k];
    float4 w = *(const float4*)(W_out + (1 + k) * NA + a);
    acc.x = fmaf(hk, w.x, acc.x); acc.y = fmaf(hk, w.y, acc.y);
    acc.z = fmaf(hk, w.z, acc.z); acc.w = fmaf(hk, w.w, acc.w);
  }
  const float emb[4] = {epx, epy, rlx, rly};
#pragma unroll
  for (int r = 0; r < 4; r++) {
    float c = emb[r];
    float4 w = *(const float4*)(W_out + (65 + r) * NA + a);
    acc.x = fmaf(c, w.x, acc.x); acc.y = fmaf(c, w.y, acc.y);
    acc.z = fmaf(c, w.z, acc.z); acc.w = fmaf(c, w.w, acc.w);
  }
  *(float4*)(pool + (size_t)i * NA + a) = acc;
}

// ---------------------------------------------------------------- y = pool @ W_mlp + b_mlp
__global__ __launch_bounds__(256) void k_gemm(const float* __restrict__ A_,
                                              const float* __restrict__ B_,
                                              const float* __restrict__ bias,
                                              float* __restrict__ C_) {
  __shared__ float As[16][64];
  __shared__ float Bs[16][64];
  int tid = threadIdx.x;
  int row0 = blockIdx.y * 64;
  int col0 = blockIdx.x * 64;
  int tx = tid & 15, ty = tid >> 4;
  int alr = tid >> 2;           // row within A tile
  int alc = (tid & 3) * 4;      // k offset
  int blr = tid >> 4;           // k within B tile
  int blc = (tid & 15) * 4;     // col offset
  float acc[4][4] = {};
  for (int k0 = 0; k0 < NA; k0 += 16) {
    float4 av = *(const float4*)(A_ + (size_t)(row0 + alr) * NA + k0 + alc);
    As[alc + 0][alr] = av.x; As[alc + 1][alr] = av.y;
    As[alc + 2][alr] = av.z; As[alc + 3][alr] = av.w;
    float4 bv = *(const float4*)(B_ + (size_t)(k0 + blr) * NA + col0 + blc);
    *(float4*)(&Bs[blr][blc]) = bv;
    __syncthreads();
#pragma unroll
    for (int kk = 0; kk < 16; kk++) {
      float4 a4 = *(const float4*)(&As[kk][ty * 4]);
      float4 b4 = *(const float4*)(&Bs[kk][tx * 4]);
      acc[0][0] = fmaf(a4.x, b4.x, acc[0][0]); acc[0][1] = fmaf(a4.x, b4.y, acc[0][1]);
      acc[0][2] = fmaf(a4.x, b4.z, acc[0][2]); acc[0][3] = fmaf(a4.x, b4.w, acc[0][3]);
      acc[1][0] = fmaf(a4.y, b4.x, acc[1][0]); acc[1][1] = fmaf(a4.y, b4.y, acc[1][1]);
      acc[1][2] = fmaf(a4.y, b4.z, acc[1][2]); acc[1][3] = fmaf(a4.y, b4.w, acc[1][3]);
      acc[2][0] = fmaf(a4.z, b4.x, acc[2][0]); acc[2][1] = fmaf(a4.z, b4.y, acc[2][1]);
      acc[2][2] = fmaf(a4.z, b4.z, acc[2][2]); acc[2][3] = fmaf(a4.z, b4.w, acc[2][3]);
      acc[3][0] = fmaf(a4.w, b4.x, acc[3][0]); acc[3][1] = fmaf(a4.w, b4.y, acc[3][1]);
      acc[3][2] = fmaf(a4.w, b4.z, acc[3][2]); acc[3][3] = fmaf(a4.w, b4.w, acc[3][3]);
    }
    __syncthreads();
  }
  float4 bb = *(const float4*)(bias + col0 + tx * 4);
#pragma unroll
  for (int m = 0; m < 4; m++) {
    float4 o;
    o.x = acc[m][0] + bb.x; o.y = acc[m][1] + bb.y;
    o.z = acc[m][2] + bb.z; o.w = acc[m][3] + bb.w;
    *(float4*)(C_ + (size_t)(row0 + ty * 4 + m) * NA + col0 + tx * 4) = o;
  }
}

// ---------------------------------------------------------------- column stats over batch
__global__ void k_stats(const float* __restrict__ y, float* __restrict__ stats) {
  int col = blockIdx.x * 256 + threadIdx.x;   // gridDim.x = 4
  int r0 = blockIdx.y * 64;                   // gridDim.y = 32
  float s = 0.0f, s2 = 0.0f;
  for (int r = r0; r < r0 + 64; r++) {
    float v = y[(size_t)r * NA + col];
    s += v; s2 = fmaf(v, v, s2);
  }
  atomicAdd(&stats[col], s);
  atomicAdd(&stats[NA + col], s2);
}

// ---------------------------------------------------------------- normalize + relu -> out
__global__ void k_norm(const float* __restrict__ y, const float* __restrict__ stats,
                       const float* __restrict__ gamma, const float* __restrict__ beta,
                       const int* __restrict__ flag, void* __restrict__ out) {
  int idx = (blockIdx.x * 256 + threadIdx.x) * 4;
  int col = idx & (NA - 1);
  float4 v  = *(const float4*)(y + idx);
  float4 s1 = *(const float4*)(stats + col);
  float4 s2 = *(const float4*)(stats + NA + col);
  float4 gm = *(const float4*)(gamma + col);
  float4 bt = *(const float4*)(beta + col);
  const float ib = 1.0f / 2048.0f;
  float o[4];
  {
    float mu = s1.x * ib; float var = fmaf(-mu, mu, s2.x * ib);
    o[0] = fmaxf(fmaf(gm.x * (v.x - mu), rsqrtf(var + 1e-5f), bt.x), 0.0f);
  }
  {
    float mu = s1.y * ib; float var = fmaf(-mu, mu, s2.y * ib);
    o[1] = fmaxf(fmaf(gm.y * (v.y - mu), rsqrtf(var + 1e-5f), bt.y), 0.0f);
  }
  {
    float mu = s1.z * ib; float var = fmaf(-mu, mu, s2.z * ib);
    o[2] = fmaxf(fmaf(gm.z * (v.z - mu), rsqrtf(var + 1e-5f), bt.z), 0.0f);
  }
  {
    float mu = s1.w * ib; float var = fmaf(-mu, mu, s2.w * ib);
    o[3] = fmaxf(fmaf(gm.w * (v.w - mu), rsqrtf(var + 1e-5f), bt.w), 0.0f);
  }
  if (flag[0]) {
    __hip_bfloat16* ob = (__hip_bfloat16*)out;
    __hip_bfloat162 p0, p1;
    p0.x = __float2bfloat16(o[0]); p0.y = __float2bfloat16(o[1]);
    p1.x = __float2bfloat16(o[2]); p1.y = __float2bfloat16(o[3]);
    *(__hip_bfloat162*)(ob + idx) = p0;
    *(__hip_bfloat162*)(ob + idx + 2) = p1;
  } else {
    float* of = (float*)out;
    *(float4*)(of + idx) = make_float4(o[0], o[1], o[2], o[3]);
  }
}

// ---------------------------------------------------------------- launch
extern "C" void kernel_launch(void* const* d_in, const int* in_sizes, int n_in,
                              void* d_out, int out_size, void* d_ws, size_t ws_size,
                              hipStream_t stream) {
  float* ws = (float*)d_ws;
  float* conv   = ws;                    // 1,594,368 floats
  float* c_h    = conv + 0;
  float* c_end  = conv + 131072;
  float* c_rel  = conv + 135168;
  float* c_scn  = conv + 139264;
  float* c_Wenc = conv + 401408;
  float* c_benc = conv + 402432;
  float* c_Wdec = conv + 403456;
  float* c_bdec = conv + 468992;
  float* c_wful = conv + 470016;
  float* c_Wout = conv + 471040;
  float* c_bout = conv + 541696;
  float* c_Wmlp = conv + 542720;
  float* c_bmlp = conv + 1591296;
  float* c_gam  = conv + 1592320;
  float* c_bet  = conv + 1593344;
  float* occ    = ws + 1594368;          // 131072
  float* pool   = ws + 1725440;          // 2097152
  float* yb     = ws + 3822592;          // 2097152
  float* stats  = ws + 5919744;          // 2048
  int*   flag   = (int*)(ws + 5921792);

  k_detect<<<1, 256, 0, stream>>>((const unsigned short*)d_in[0], flag);

  InPtrs ptrs;
  ptrs.p[0] = d_in[0];  ptrs.p[1] = d_in[1];  ptrs.p[2] = d_in[2];
  ptrs.p[3] = d_in[3];  ptrs.p[4] = d_in[4];  ptrs.p[5] = d_in[5];
  ptrs.p[6] = d_in[6];  ptrs.p[7] = d_in[7];  ptrs.p[8] = d_in[8];
  ptrs.p[9] = d_in[10]; ptrs.p[10] = d_in[11]; ptrs.p[11] = d_in[12];
  ptrs.p[12] = d_in[13]; ptrs.p[13] = d_in[14]; ptrs.p[14] = d_in[15];
  k_convert<<<1557, 256, 0, stream>>>(ptrs, flag, conv);   // 1557*256*4 = 1,594,368

  k_occupancy<<<NPED, 256, 0, stream>>>(c_end, c_scn, occ);

  k_attn_pool<<<NPED, 256, 0, stream>>>(c_h, c_end, c_rel, occ, c_Wenc, c_benc,
                                        c_Wdec, c_bdec, c_wful, c_Wout, c_bout, pool);

  hipMemsetAsync(stats, 0, 2 * NA * sizeof(float), stream);

  dim3 gg(16, 32);
  k_gemm<<<gg, 256, 0, stream>>>(pool, c_Wmlp, c_bmlp, yb);

  dim3 gs(4, 32);
  k_stats<<<gs, 256, 0, stream>>>(yb, stats);

  k_norm<<<2048, 256, 0, stream>>>(yb, stats, c_gam, c_bet, flag, d_out);
}